// Round 6
// baseline (97.195 us; speedup 1.0000x reference)
//
#include <hip/hip_runtime.h>
#include <math.h>

// SplitBruteForceAntisymmetrize: N=6 (720 perms), D=3, HID=64, BATCH=2048.
// Math (R3+R4, measured absmax 0.1875):
//   F[j][i] = exp2(K*c[j][i]) (K=2log2e, b1 folded into col 0); 2^{preact'} =
//   prod_i F[perm(i)][i]; tanh = 1 - 2/(E+1); sum_p sign_p = 0.
//   Pair {a<b} after 4-slot prefix P: d = P*(v-u)/(P^2*u*v + P*(u+v) + 1).
//   Depth-3 triple-combine: 3 children merged over common denominator ->
//   ONE rcp + ONE fp64 add per 6 perms. Signed fold in fp64 (R2 lesson:
//   S ~ 1e-5 vs O(1) terms; fp32 running sums are fatal).
// R6 schedule change (math identical):
//   grid 512, each wave loops over 2 (b,ch) jobs; __launch_bounds__(256,2)
//   -> VGPR cap 256 (no spill possible), exactly 2 blocks/CU resident ->
//   ZERO dispatch tail (R5 post-mortem: grid 1024 at 3-blocks/CU residency
//   paid ~4/3x). Weights w1c/b1s/w2v hoisted out of the loop; iteration 2
//   runs with warm I$. TLP = 2 waves/SIMD, covered by node-level ILP.
// Overflow: den = prod of 6 (E+1)-like factors <= ~2^93 at data tails < 2^127.

__device__ __forceinline__ float fexp2(float x) {
#if __has_builtin(__builtin_amdgcn_exp2f)
    return __builtin_amdgcn_exp2f(x);
#else
    return exp2f(x);
#endif
}
__device__ __forceinline__ float frcp(float x) {
#if __has_builtin(__builtin_amdgcn_rcpf)
    return __builtin_amdgcn_rcpf(x);
#else
    return 1.0f / x;
#endif
}

constexpr int lowest_free(unsigned used) {
    for (int j = 0; j < 6; ++j)
        if (!(used & (1u << j))) return j;
    return -1;
}

struct Tbl {
    float F[6][4];   // F[j][i] for slots 0..3 (cols 4,5 live only in w/s/q)
    float w[6][6];   // w[a][b] = v-u   (a<b only)
    float s[6][6];   // s[a][b] = u+v   (a<b only)
    float q[6][6];   // q[a][b] = u*v   (a<b only)
};

// Generic DFS over slots 0..2; P = running product of F factors.
template <int LVL, unsigned USED, int PAR>
struct Node {
    template <int J>
    static __device__ __forceinline__ void step(const Tbl& T, float P,
                                                double& a0, double& a1) {
        if constexpr ((USED & (1u << J)) == 0) {
            constexpr int par2 = PAR ^ (__builtin_popcount(USED >> (J + 1)) & 1);
            if constexpr (LVL == 0)
                Node<1, (1u << J), par2>::go(T, T.F[J][0], a0, a1);
            else
                Node<LVL + 1, USED | (1u << J), par2>::go(T, P * T.F[J][LVL], a0, a1);
        }
    }
    static __device__ __forceinline__ void go(const Tbl& T, float P,
                                              double& a0, double& a1) {
        step<0>(T, P, a0, a1);
        step<1>(T, P, a0, a1);
        step<2>(T, P, a0, a1);
        step<3>(T, P, a0, a1);
        step<4>(T, P, a0, a1);
        step<5>(T, P, a0, a1);
    }
};

// Depth-3 node: slots 0-2 placed; 3 free -> 3 children (x@slot3), each leaving
// transposition pair {a<b}; merged over common denominator.
template <unsigned USED, int PAR>
struct Node<3, USED, PAR> {
    template <int X, int A, int B>
    static __device__ __forceinline__ float child_den(const Tbl& T, float P3,
                                                      float& n) {
        float P4 = P3 * T.F[X][3];
        float Q  = P4 * P4;
        n = P4 * T.w[A][B];
        return fmaf(Q, T.q[A][B], fmaf(P4, T.s[A][B], 1.0f));
    }
    template <int X, int A, int B>
    static constexpr int child_sign() {
        constexpr unsigned U4 = USED | (1u << X);
        constexpr int inv_x = __builtin_popcount(USED >> (X + 1));
        constexpr int inv_a = __builtin_popcount(U4 >> (A + 1));
        constexpr int inv_b = __builtin_popcount((U4 | (1u << A)) >> (B + 1));
        return (PAR ^ ((inv_x + inv_a + inv_b) & 1));
    }
    static __device__ __forceinline__ void go(const Tbl& T, float P3,
                                              double& a0, double& a1) {
        constexpr int x0 = lowest_free(USED);
        constexpr int x1 = lowest_free(USED | (1u << x0));
        constexpr int x2 = lowest_free(USED | (1u << x0) | (1u << x1));
        constexpr float sg0 = child_sign<x0, x1, x2>() ? -1.0f : 1.0f;
        constexpr float sg1 = child_sign<x1, x0, x2>() ? -1.0f : 1.0f;
        constexpr float sg2 = child_sign<x2, x0, x1>() ? -1.0f : 1.0f;

        float n0, n1, n2;
        float den0 = child_den<x0, x1, x2>(T, P3, n0);
        float den1 = child_den<x1, x0, x2>(T, P3, n1);
        float den2 = child_den<x2, x0, x1>(T, P3, n2);

        float d01 = den0 * den1;
        float den = d01 * den2;
        float t01 = (sg0 * n0) * den1 + (sg1 * n1) * den0;
        float num = t01 * den2 + (sg2 * n2) * d01;
        float r = num * frcp(den);
        if constexpr (USED & 1) a1 += (double)r;
        else                    a0 += (double)r;
    }
};

__global__ __launch_bounds__(256, 2) void antisym_kernel(
    const float* __restrict__ x1, const float* __restrict__ x2,
    const float* __restrict__ W1a, const float* __restrict__ b1a,
    const float* __restrict__ W2a,
    const float* __restrict__ W1b, const float* __restrict__ b1b,
    const float* __restrict__ W2b,
    float* __restrict__ out, int B) {
    __shared__ float lds_log[4];

    const int lane = threadIdx.x & 63;
    const int wave = threadIdx.x >> 6;
    const int ch = wave & 1;

    // Loop-invariant: per-channel weights, pre-scaled by K = 2*log2(e).
    const float* W1 = ch ? W1b : W1a;
    const float* b1 = ch ? b1b : b1a;
    const float* W2 = ch ? W2b : W2a;
    const float* x  = ch ? x2  : x1;

    const float K = 2.8853900817779268f;
    float w1c[18];
#pragma unroll
    for (int r = 0; r < 18; ++r) w1c[r] = W1[r * 64 + lane] * K;
    const float b1s = b1[lane] * K;
    const float w2v = W2[lane];

#pragma unroll
    for (int it = 0; it < 2; ++it) {
        const int b = blockIdx.x * 4 + it * 2 + (wave >> 1);
        if (b < B) {
            float xv[18];
            const float* xb = x + b * 18;
#pragma unroll
            for (int r = 0; r < 18; ++r) xv[r] = xb[r];

            Tbl T;
            float F4[6], F5[6], g[6];
#pragma unroll
            for (int j = 0; j < 6; ++j) {
#pragma unroll
                for (int i = 0; i < 6; ++i) {
                    float c = xv[j * 3 + 0] * w1c[i * 3 + 0] +
                              xv[j * 3 + 1] * w1c[i * 3 + 1] +
                              xv[j * 3 + 2] * w1c[i * 3 + 2];
                    if (i == 0) c += b1s;
                    float e = fexp2(c);
                    if (i < 4) T.F[j][i] = e;
                    else if (i == 4) F4[j] = e;
                    else F5[j] = e;
                }
                g[j] = F4[j] * F5[j];
            }
#pragma unroll
            for (int a = 0; a < 6; ++a)
#pragma unroll
                for (int bb = a + 1; bb < 6; ++bb) {
                    float u = F4[a] * F5[bb];   // (a@4, b@5)
                    float v = F4[bb] * F5[a];   // (b@4, a@5)
                    T.w[a][bb] = v - u;
                    T.s[a][bb] = u + v;
                    T.q[a][bb] = g[a] * g[bb];
                }

            double acc0 = 0.0, acc1 = 0.0;
            Node<0, 0u, 0>::go(T, 1.0f, acc0, acc1);

            // psi_lane = -2 * w2 * S ; b2 contributes b2*sum(signs) = 0
            double v = (double)w2v * (acc0 + acc1) * -2.0;
#pragma unroll
            for (int off = 32; off > 0; off >>= 1) v += __shfl_xor(v, off, 64);

            if (lane == 0) lds_log[wave] = logf(fabsf((float)v));
        }
        __syncthreads();
        if (threadIdx.x < 2) {
            int bb = blockIdx.x * 4 + it * 2 + threadIdx.x;
            if (bb < B)
                out[bb] = lds_log[threadIdx.x * 2] + lds_log[threadIdx.x * 2 + 1];
        }
        __syncthreads();  // protect lds_log before next iteration's writes
    }
}

extern "C" void kernel_launch(void* const* d_in, const int* in_sizes, int n_in,
                              void* d_out, int out_size, void* d_ws, size_t ws_size,
                              hipStream_t stream) {
    const float* x1  = (const float*)d_in[0];
    const float* x2  = (const float*)d_in[1];
    const float* W1a = (const float*)d_in[2];
    const float* b1a = (const float*)d_in[3];
    const float* W2a = (const float*)d_in[4];
    // d_in[5] = b2a: contributes b2 * sum(signs) = 0 exactly
    const float* W1b = (const float*)d_in[6];
    const float* b1b = (const float*)d_in[7];
    const float* W2b = (const float*)d_in[8];
    // d_in[9] = b2b: same

    const int B = in_sizes[0] / 18;  // (B, 6, 3) flattened
    float* out = (float*)d_out;

    dim3 grid((B + 3) / 4), block(256);  // 4 batch per block (2 per iteration)
    hipLaunchKernelGGL(antisym_kernel, grid, block, 0, stream,
                       x1, x2, W1a, b1a, W2a, W1b, b1b, W2b, out, B);
}

// Round 7
// 87.469 us; speedup vs baseline: 1.1112x; 1.1112x over previous
//
#include <hip/hip_runtime.h>
#include <math.h>

// SplitBruteForceAntisymmetrize: N=6 (720 perms), D=3, HID=64, BATCH=2048.
// Math (R3+R4, measured absmax 0.1875):
//   F[j][i] = exp2(K*c[j][i]) (K=2log2e, b1 folded into col 0); 2^{preact'} =
//   prod_i F[perm(i)][i]; tanh = 1 - 2/(E+1); sum_p sign_p = 0.
//   Pair {a<b} after 4-slot prefix P: d = P*(v-u)/(P^2*u*v + P*(u+v) + 1).
//   Depth-3 triple-combine: 3 children merged over common denominator ->
//   ONE rcp + ONE fp64 add per 6 perms. Signed fold in fp64 (R2 lesson).
// R7 (single idea): PACKED DUAL-BATCH. Each wave computes TWO batch elements,
//   one in each half of packed-f32 vectors -> every f32 op becomes
//   v_pk_mul/fma_f32 (m07: scalar v_fma = ~3cyc/66% of peak; packed math is
//   the only road to the 157 TF rate). Same instruction count as one R5 job,
//   two jobs done. exp2/rcp/f64 have no packed form -> unchanged per job.
//   R5/R6 showed the kernel is issue-bound (time ~ total issue slots, weak
//   TLP sensitivity), so halving the f32 stream per job is the lever.
// Schedule: grid 512, __launch_bounds__(256,2) -> VGPR cap 256 (live ~200,
//   no spill), exactly 2 blocks/CU resident, zero dispatch tail.
// Overflow: den = prod of 6 (E+1)-like factors <= ~2^93 at data tails < 2^127.

typedef float  v2f __attribute__((ext_vector_type(2)));
typedef double v2d __attribute__((ext_vector_type(2)));

__device__ __forceinline__ float fexp2(float x) {
#if __has_builtin(__builtin_amdgcn_exp2f)
    return __builtin_amdgcn_exp2f(x);
#else
    return exp2f(x);
#endif
}
__device__ __forceinline__ float frcp(float x) {
#if __has_builtin(__builtin_amdgcn_rcpf)
    return __builtin_amdgcn_rcpf(x);
#else
    return 1.0f / x;
#endif
}
__device__ __forceinline__ v2f vrcp(v2f v) {
    v2f r; r.x = frcp(v.x); r.y = frcp(v.y); return r;
}
__device__ __forceinline__ v2f vfma(v2f a, v2f b, v2f c) {
    return __builtin_elementwise_fma(a, b, c);
}

constexpr int lowest_free(unsigned used) {
    for (int j = 0; j < 6; ++j)
        if (!(used & (1u << j))) return j;
    return -1;
}

struct Tbl {
    v2f F[6][4];   // F[j][i] for slots 0..3 (cols 4,5 live only in w/s/q)
    v2f w[6][6];   // w[a][b] = v-u   (a<b only)
    v2f s[6][6];   // s[a][b] = u+v   (a<b only)
    v2f q[6][6];   // q[a][b] = u*v   (a<b only)
};

// Generic DFS over slots 0..2; P = running product of F factors (packed pair).
template <int LVL, unsigned USED, int PAR>
struct Node {
    template <int J>
    static __device__ __forceinline__ void step(const Tbl& T, v2f P,
                                                v2d& a0, v2d& a1) {
        if constexpr ((USED & (1u << J)) == 0) {
            constexpr int par2 = PAR ^ (__builtin_popcount(USED >> (J + 1)) & 1);
            if constexpr (LVL == 0)
                Node<1, (1u << J), par2>::go(T, T.F[J][0], a0, a1);
            else
                Node<LVL + 1, USED | (1u << J), par2>::go(T, P * T.F[J][LVL], a0, a1);
        }
    }
    static __device__ __forceinline__ void go(const Tbl& T, v2f P,
                                              v2d& a0, v2d& a1) {
        step<0>(T, P, a0, a1);
        step<1>(T, P, a0, a1);
        step<2>(T, P, a0, a1);
        step<3>(T, P, a0, a1);
        step<4>(T, P, a0, a1);
        step<5>(T, P, a0, a1);
    }
};

// Depth-3 node: slots 0-2 placed; 3 free -> 3 children (x@slot3), each leaving
// transposition pair {a<b}; merged over common denominator.
template <unsigned USED, int PAR>
struct Node<3, USED, PAR> {
    template <int X, int A, int B>
    static __device__ __forceinline__ v2f child_den(const Tbl& T, v2f P3,
                                                    v2f& n) {
        v2f P4 = P3 * T.F[X][3];
        v2f Q  = P4 * P4;
        n = P4 * T.w[A][B];
        v2f one; one.x = 1.0f; one.y = 1.0f;
        return vfma(Q, T.q[A][B], vfma(P4, T.s[A][B], one));
    }
    template <int X, int A, int B>
    static constexpr int child_sign() {
        constexpr unsigned U4 = USED | (1u << X);
        constexpr int inv_x = __builtin_popcount(USED >> (X + 1));
        constexpr int inv_a = __builtin_popcount(U4 >> (A + 1));
        constexpr int inv_b = __builtin_popcount((U4 | (1u << A)) >> (B + 1));
        return (PAR ^ ((inv_x + inv_a + inv_b) & 1));
    }
    static __device__ __forceinline__ void go(const Tbl& T, v2f P3,
                                              v2d& a0, v2d& a1) {
        constexpr int x0 = lowest_free(USED);
        constexpr int x1 = lowest_free(USED | (1u << x0));
        constexpr int x2 = lowest_free(USED | (1u << x0) | (1u << x1));

        v2f n0, n1, n2;
        v2f den0 = child_den<x0, x1, x2>(T, P3, n0);
        v2f den1 = child_den<x1, x0, x2>(T, P3, n1);
        v2f den2 = child_den<x2, x0, x1>(T, P3, n2);

        // signs folded into operands (neg modifier is free in VOP3P)
        v2f n0s = child_sign<x0, x1, x2>() ? -n0 : n0;
        v2f n1s = child_sign<x1, x0, x2>() ? -n1 : n1;
        v2f n2s = child_sign<x2, x0, x1>() ? -n2 : n2;

        v2f d01 = den0 * den1;
        v2f den = d01 * den2;
        v2f t01 = vfma(n0s, den1, n1s * den0);
        v2f num = vfma(t01, den2, n2s * d01);
        v2f r = num * vrcp(den);
        v2d rd = __builtin_convertvector(r, v2d);
        if constexpr (USED & 1) a1 += rd;
        else                    a0 += rd;
    }
};

__global__ __launch_bounds__(256, 2) void antisym_kernel(
    const float* __restrict__ x1, const float* __restrict__ x2,
    const float* __restrict__ W1a, const float* __restrict__ b1a,
    const float* __restrict__ W2a,
    const float* __restrict__ W1b, const float* __restrict__ b1b,
    const float* __restrict__ W2b,
    float* __restrict__ out, int B) {
    __shared__ float lds_log[8];   // [(pair*2+k)*2 + ch]

    const int lane = threadIdx.x & 63;
    const int wave = threadIdx.x >> 6;
    const int pi = wave >> 1;      // batch-pair index within block
    const int ch = wave & 1;

    const float* x  = ch ? x2  : x1;
    const float* W1 = ch ? W1b : W1a;
    const float* b1 = ch ? b1b : b1a;
    const float* W2 = ch ? W2b : W2a;

    const int b0 = blockIdx.x * 4 + pi * 2;
    const int b1i = b0 + 1;
    const int b1c = (b1i < B) ? b1i : (B - 1);

    if (b0 < B) {
        const float K = 2.8853900817779268f;  // 2*log2(e)

        float w1c[18];
#pragma unroll
        for (int r = 0; r < 18; ++r) w1c[r] = W1[r * 64 + lane] * K;
        const float b1s = b1[lane] * K;
        const float w2v = W2[lane];

        // xv: job0 in .x, job1 in .y
        v2f xv[18];
        const float* xa = x + b0 * 18;
        const float* xb = x + b1c * 18;
#pragma unroll
        for (int r = 0; r < 18; ++r) { xv[r].x = xa[r]; xv[r].y = xb[r]; }

        Tbl T;
        v2f F4[6], F5[6], g[6];
#pragma unroll
        for (int j = 0; j < 6; ++j) {
#pragma unroll
            for (int i = 0; i < 6; ++i) {
                v2f c = xv[j * 3 + 0] * w1c[i * 3 + 0] +
                        xv[j * 3 + 1] * w1c[i * 3 + 1] +
                        xv[j * 3 + 2] * w1c[i * 3 + 2];
                if (i == 0) { c.x += b1s; c.y += b1s; }
                v2f e; e.x = fexp2(c.x); e.y = fexp2(c.y);
                if (i < 4) T.F[j][i] = e;
                else if (i == 4) F4[j] = e;
                else F5[j] = e;
            }
            g[j] = F4[j] * F5[j];
        }
#pragma unroll
        for (int a = 0; a < 6; ++a)
#pragma unroll
            for (int bb = a + 1; bb < 6; ++bb) {
                v2f u = F4[a] * F5[bb];   // (a@4, b@5)
                v2f v = F4[bb] * F5[a];   // (b@4, a@5)
                T.w[a][bb] = v - u;
                T.s[a][bb] = u + v;
                T.q[a][bb] = g[a] * g[bb];
            }

        v2d acc0; acc0.x = 0.0; acc0.y = 0.0;
        v2d acc1; acc1.x = 0.0; acc1.y = 0.0;
        v2f one; one.x = 1.0f; one.y = 1.0f;
        Node<0, 0u, 0>::go(T, one, acc0, acc1);

        // psi = -2 * w2 * S per job; b2 contributes b2*sum(signs) = 0
        double v0 = (double)w2v * (acc0.x + acc1.x) * -2.0;
        double v1 = (double)w2v * (acc0.y + acc1.y) * -2.0;
#pragma unroll
        for (int off = 32; off > 0; off >>= 1) {
            v0 += __shfl_xor(v0, off, 64);
            v1 += __shfl_xor(v1, off, 64);
        }

        if (lane == 0) {
            lds_log[(pi * 2 + 0) * 2 + ch] = logf(fabsf((float)v0));
            if (b1i < B)
                lds_log[(pi * 2 + 1) * 2 + ch] = logf(fabsf((float)v1));
        }
    }
    __syncthreads();
    if (threadIdx.x < 4) {
        int bb = blockIdx.x * 4 + threadIdx.x;
        if (bb < B)
            out[bb] = lds_log[threadIdx.x * 2 + 0] + lds_log[threadIdx.x * 2 + 1];
    }
}

extern "C" void kernel_launch(void* const* d_in, const int* in_sizes, int n_in,
                              void* d_out, int out_size, void* d_ws, size_t ws_size,
                              hipStream_t stream) {
    const float* x1  = (const float*)d_in[0];
    const float* x2  = (const float*)d_in[1];
    const float* W1a = (const float*)d_in[2];
    const float* b1a = (const float*)d_in[3];
    const float* W2a = (const float*)d_in[4];
    // d_in[5] = b2a: contributes b2 * sum(signs) = 0 exactly
    const float* W1b = (const float*)d_in[6];
    const float* b1b = (const float*)d_in[7];
    const float* W2b = (const float*)d_in[8];
    // d_in[9] = b2b: same

    const int B = in_sizes[0] / 18;  // (B, 6, 3) flattened
    float* out = (float*)d_out;

    dim3 grid((B + 3) / 4), block(256);  // 4 batch per block (2 per wave, packed)
    hipLaunchKernelGGL(antisym_kernel, grid, block, 0, stream,
                       x1, x2, W1a, b1a, W2a, W1b, b1b, W2b, out, B);
}

// Round 8
// 87.066 us; speedup vs baseline: 1.1163x; 1.0046x over previous
//
#include <hip/hip_runtime.h>
#include <math.h>

// SplitBruteForceAntisymmetrize: N=6 (720 perms), D=3, HID=64, BATCH=2048.
// Math (R3+R4, measured absmax 0.1875):
//   F[j][i] = exp2(K*c[j][i]) (K=2log2e, b1 folded into col 0); 2^{preact'} =
//   prod_i F[perm(i)][i]; tanh = 1 - 2/(E+1); sum_p sign_p = 0.
//   Pair {a<b} after 4-slot prefix P: d = P*(v-u)/(P^2*u*v + P*(u+v) + 1).
//   Depth-3 triple-combine: 3 children merged over common denominator ->
//   ONE rcp + ONE fp64 add per 6 perms. Signed fold in fp64 (R2 lesson).
//   Packed dual-batch (R7): two batch elems in v2f halves -> v_pk_* f32 ops.
// R8 root-cause fix (math identical): R7's rocprof showed VGPR_Count=88 <
//   the 174-reg packed table set, VALUBusy 22%, profiled dur 60us -> LLVM
//   promote-alloca put ALL array aggregates in SCRATCH (explains R1's
//   VGPR=32 and the 2.2x model gap since R4). Replace every aggregate with
//   NAMED struct members + if-constexpr template getters/setters: trivially
//   SROA-able -> guaranteed VGPRs. Live set ~190 < 256 cap from
//   __launch_bounds__(256,2); grid 512 = exactly 2 blocks/CU, zero tail.
// Overflow: den = prod of 6 (E+1)-like factors <= ~2^93 at data tails < 2^127.

typedef float  v2f __attribute__((ext_vector_type(2)));
typedef double v2d __attribute__((ext_vector_type(2)));

__device__ __forceinline__ float fexp2(float x) {
#if __has_builtin(__builtin_amdgcn_exp2f)
    return __builtin_amdgcn_exp2f(x);
#else
    return exp2f(x);
#endif
}
__device__ __forceinline__ float frcp(float x) {
#if __has_builtin(__builtin_amdgcn_rcpf)
    return __builtin_amdgcn_rcpf(x);
#else
    return 1.0f / x;
#endif
}
__device__ __forceinline__ v2f vrcp(v2f v) {
    v2f r; r.x = frcp(v.x); r.y = frcp(v.y); return r;
}
__device__ __forceinline__ v2f vfma(v2f a, v2f b, v2f c) {
    return __builtin_elementwise_fma(a, b, c);
}

constexpr int lowest_free(unsigned used) {
    for (int j = 0; j < 6; ++j)
        if (!(used & (1u << j))) return j;
    return -1;
}

// ---- named-member tables (NO arrays anywhere -> no alloca -> no scratch) ----
#define FJI_LIST(X) X(0,0) X(0,1) X(0,2) X(0,3) X(1,0) X(1,1) X(1,2) X(1,3) \
                    X(2,0) X(2,1) X(2,2) X(2,3) X(3,0) X(3,1) X(3,2) X(3,3) \
                    X(4,0) X(4,1) X(4,2) X(4,3) X(5,0) X(5,1) X(5,2) X(5,3)
#define J6_LIST(X) X(0) X(1) X(2) X(3) X(4) X(5)
#define PAIR_LIST(X) X(0,1) X(0,2) X(0,3) X(0,4) X(0,5) X(1,2) X(1,3) X(1,4) \
                     X(1,5) X(2,3) X(2,4) X(2,5) X(3,4) X(3,5) X(4,5)
#define WC_LIST(X) X(0) X(1) X(2) X(3) X(4) X(5) X(6) X(7) X(8) X(9) X(10) \
                   X(11) X(12) X(13) X(14) X(15) X(16) X(17)

struct Tbl {
#define M(j,i) v2f F##j##_##i;
    FJI_LIST(M)
#undef M
#define M(j) v2f FA##j; v2f FB##j; v2f G##j;
    J6_LIST(M)
#undef M
#define M(a,b) v2f W##a##b; v2f S##a##b; v2f Q##a##b;
    PAIR_LIST(M)
#undef M
};

template <int J, int I> __device__ __forceinline__ v2f getF(const Tbl& T) {
#define M(j,i) if constexpr (J==j && I==i) return T.F##j##_##i;
    FJI_LIST(M)
#undef M
    __builtin_unreachable();
}
template <int J, int I> __device__ __forceinline__ void setF(Tbl& T, v2f v) {
#define M(j,i) if constexpr (J==j && I==i) T.F##j##_##i = v;
    FJI_LIST(M)
#undef M
}
template <int J> __device__ __forceinline__ v2f getFA(const Tbl& T) {
#define M(j) if constexpr (J==j) return T.FA##j;
    J6_LIST(M)
#undef M
    __builtin_unreachable();
}
template <int J> __device__ __forceinline__ void setFA(Tbl& T, v2f v) {
#define M(j) if constexpr (J==j) T.FA##j = v;
    J6_LIST(M)
#undef M
}
template <int J> __device__ __forceinline__ v2f getFB(const Tbl& T) {
#define M(j) if constexpr (J==j) return T.FB##j;
    J6_LIST(M)
#undef M
    __builtin_unreachable();
}
template <int J> __device__ __forceinline__ void setFB(Tbl& T, v2f v) {
#define M(j) if constexpr (J==j) T.FB##j = v;
    J6_LIST(M)
#undef M
}
template <int J> __device__ __forceinline__ v2f getG(const Tbl& T) {
#define M(j) if constexpr (J==j) return T.G##j;
    J6_LIST(M)
#undef M
    __builtin_unreachable();
}
template <int J> __device__ __forceinline__ void setG(Tbl& T, v2f v) {
#define M(j) if constexpr (J==j) T.G##j = v;
    J6_LIST(M)
#undef M
}
template <int A, int B> __device__ __forceinline__ v2f getW(const Tbl& T) {
#define M(a,b) if constexpr (A==a && B==b) return T.W##a##b;
    PAIR_LIST(M)
#undef M
    __builtin_unreachable();
}
template <int A, int B> __device__ __forceinline__ void setW(Tbl& T, v2f v) {
#define M(a,b) if constexpr (A==a && B==b) T.W##a##b = v;
    PAIR_LIST(M)
#undef M
}
template <int A, int B> __device__ __forceinline__ v2f getS(const Tbl& T) {
#define M(a,b) if constexpr (A==a && B==b) return T.S##a##b;
    PAIR_LIST(M)
#undef M
    __builtin_unreachable();
}
template <int A, int B> __device__ __forceinline__ void setS(Tbl& T, v2f v) {
#define M(a,b) if constexpr (A==a && B==b) T.S##a##b = v;
    PAIR_LIST(M)
#undef M
}
template <int A, int B> __device__ __forceinline__ v2f getQ(const Tbl& T) {
#define M(a,b) if constexpr (A==a && B==b) return T.Q##a##b;
    PAIR_LIST(M)
#undef M
    __builtin_unreachable();
}
template <int A, int B> __device__ __forceinline__ void setQ(Tbl& T, v2f v) {
#define M(a,b) if constexpr (A==a && B==b) T.Q##a##b = v;
    PAIR_LIST(M)
#undef M
}

// per-lane weights, pre-scaled by K = 2*log2(e); named scalars only
struct Wgt {
#define M(r) float c##r;
    WC_LIST(M)
#undef M
    float b1s;
};
template <int R> __device__ __forceinline__ float getWC(const Wgt& W) {
#define M(r) if constexpr (R==r) return W.c##r;
    WC_LIST(M)
#undef M
    __builtin_unreachable();
}

// ---- setup: c -> exp2 -> F/FA/FB/G, then pair tables W/S/Q ----
template <int J, int I>
__device__ __forceinline__ void setupJI(Tbl& T, const Wgt& Wg,
                                        v2f x0, v2f x1, v2f x2) {
    v2f c = x0 * getWC<3*I+0>(Wg) + x1 * getWC<3*I+1>(Wg) + x2 * getWC<3*I+2>(Wg);
    if constexpr (I == 0) { c.x += Wg.b1s; c.y += Wg.b1s; }
    v2f e; e.x = fexp2(c.x); e.y = fexp2(c.y);
    if constexpr (I < 4) setF<J, I>(T, e);
    else if constexpr (I == 4) setFA<J>(T, e);
    else { setFB<J>(T, e); setG<J>(T, getFA<J>(T) * e); }
}

template <int J>
__device__ __forceinline__ void setupJ(Tbl& T, const Wgt& Wg,
                                       const float* xa, const float* xb) {
    v2f x0, x1, x2;
    x0.x = xa[3*J+0]; x0.y = xb[3*J+0];
    x1.x = xa[3*J+1]; x1.y = xb[3*J+1];
    x2.x = xa[3*J+2]; x2.y = xb[3*J+2];
    setupJI<J,0>(T, Wg, x0, x1, x2);
    setupJI<J,1>(T, Wg, x0, x1, x2);
    setupJI<J,2>(T, Wg, x0, x1, x2);
    setupJI<J,3>(T, Wg, x0, x1, x2);
    setupJI<J,4>(T, Wg, x0, x1, x2);
    setupJI<J,5>(T, Wg, x0, x1, x2);
}

template <int A, int B>
__device__ __forceinline__ void setupPair(Tbl& T) {
    v2f u = getFA<A>(T) * getFB<B>(T);   // (a@4, b@5)
    v2f v = getFA<B>(T) * getFB<A>(T);   // (b@4, a@5)
    setW<A,B>(T, v - u);
    setS<A,B>(T, u + v);
    setQ<A,B>(T, getG<A>(T) * getG<B>(T));
}

// ---- DFS over slots 0..2; P = running packed product of F factors ----
template <int LVL, unsigned USED, int PAR>
struct Node {
    template <int J>
    static __device__ __forceinline__ void step(const Tbl& T, v2f P,
                                                v2d& a0, v2d& a1) {
        if constexpr ((USED & (1u << J)) == 0) {
            constexpr int par2 = PAR ^ (__builtin_popcount(USED >> (J + 1)) & 1);
            if constexpr (LVL == 0)
                Node<1, (1u << J), par2>::go(T, getF<J,0>(T), a0, a1);
            else
                Node<LVL + 1, USED | (1u << J), par2>::go(T, P * getF<J,LVL>(T), a0, a1);
        }
    }
    static __device__ __forceinline__ void go(const Tbl& T, v2f P,
                                              v2d& a0, v2d& a1) {
        step<0>(T, P, a0, a1);
        step<1>(T, P, a0, a1);
        step<2>(T, P, a0, a1);
        step<3>(T, P, a0, a1);
        step<4>(T, P, a0, a1);
        step<5>(T, P, a0, a1);
    }
};

// Depth-3 node: slots 0-2 placed; 3 free -> 3 children (x@slot3), each leaving
// transposition pair {a<b}; merged over common denominator.
template <unsigned USED, int PAR>
struct Node<3, USED, PAR> {
    template <int X, int A, int B>
    static __device__ __forceinline__ v2f child_den(const Tbl& T, v2f P3,
                                                    v2f& n) {
        v2f P4 = P3 * getF<X,3>(T);
        v2f Q  = P4 * P4;
        n = P4 * getW<A,B>(T);
        v2f one; one.x = 1.0f; one.y = 1.0f;
        return vfma(Q, getQ<A,B>(T), vfma(P4, getS<A,B>(T), one));
    }
    template <int X, int A, int B>
    static constexpr int child_sign() {
        constexpr unsigned U4 = USED | (1u << X);
        constexpr int inv_x = __builtin_popcount(USED >> (X + 1));
        constexpr int inv_a = __builtin_popcount(U4 >> (A + 1));
        constexpr int inv_b = __builtin_popcount((U4 | (1u << A)) >> (B + 1));
        return (PAR ^ ((inv_x + inv_a + inv_b) & 1));
    }
    static __device__ __forceinline__ void go(const Tbl& T, v2f P3,
                                              v2d& a0, v2d& a1) {
        constexpr int x0 = lowest_free(USED);
        constexpr int x1 = lowest_free(USED | (1u << x0));
        constexpr int x2 = lowest_free(USED | (1u << x0) | (1u << x1));

        v2f n0, n1, n2;
        v2f den0 = child_den<x0, x1, x2>(T, P3, n0);
        v2f den1 = child_den<x1, x0, x2>(T, P3, n1);
        v2f den2 = child_den<x2, x0, x1>(T, P3, n2);

        v2f n0s = child_sign<x0, x1, x2>() ? -n0 : n0;
        v2f n1s = child_sign<x1, x0, x2>() ? -n1 : n1;
        v2f n2s = child_sign<x2, x0, x1>() ? -n2 : n2;

        v2f d01 = den0 * den1;
        v2f den = d01 * den2;
        v2f t01 = vfma(n0s, den1, n1s * den0);
        v2f num = vfma(t01, den2, n2s * d01);
        v2f r = num * vrcp(den);
        v2d rd = __builtin_convertvector(r, v2d);
        if constexpr (USED & 1) a1 += rd;
        else                    a0 += rd;
    }
};

__global__ __launch_bounds__(256, 2) void antisym_kernel(
    const float* __restrict__ x1, const float* __restrict__ x2,
    const float* __restrict__ W1a, const float* __restrict__ b1a,
    const float* __restrict__ W2a,
    const float* __restrict__ W1b, const float* __restrict__ b1b,
    const float* __restrict__ W2b,
    float* __restrict__ out, int B) {
    __shared__ float lds_log[8];   // [(pair*2+k)*2 + ch]

    const int lane = threadIdx.x & 63;
    const int wave = threadIdx.x >> 6;
    const int pi = wave >> 1;      // batch-pair index within block
    const int ch = wave & 1;

    const float* x  = ch ? x2  : x1;
    const float* W1 = ch ? W1b : W1a;
    const float* b1 = ch ? b1b : b1a;
    const float* W2 = ch ? W2b : W2a;

    const int b0 = blockIdx.x * 4 + pi * 2;
    const int b1i = b0 + 1;
    const int b1c = (b1i < B) ? b1i : (B - 1);

    if (b0 < B) {
        const float K = 2.8853900817779268f;  // 2*log2(e)

        Wgt Wg;
#define M(r) Wg.c##r = W1[r * 64 + lane] * K;
        WC_LIST(M)
#undef M
        Wg.b1s = b1[lane] * K;
        const float w2v = W2[lane];

        const float* xa = x + b0 * 18;
        const float* xb = x + b1c * 18;

        Tbl T;
        setupJ<0>(T, Wg, xa, xb);
        setupJ<1>(T, Wg, xa, xb);
        setupJ<2>(T, Wg, xa, xb);
        setupJ<3>(T, Wg, xa, xb);
        setupJ<4>(T, Wg, xa, xb);
        setupJ<5>(T, Wg, xa, xb);
#define M(a,b) setupPair<a,b>(T);
        PAIR_LIST(M)
#undef M

        v2d acc0; acc0.x = 0.0; acc0.y = 0.0;
        v2d acc1; acc1.x = 0.0; acc1.y = 0.0;
        v2f one; one.x = 1.0f; one.y = 1.0f;
        Node<0, 0u, 0>::go(T, one, acc0, acc1);

        // psi = -2 * w2 * S per job; b2 contributes b2*sum(signs) = 0
        double v0 = (double)w2v * (acc0.x + acc1.x) * -2.0;
        double v1 = (double)w2v * (acc0.y + acc1.y) * -2.0;
#pragma unroll
        for (int off = 32; off > 0; off >>= 1) {
            v0 += __shfl_xor(v0, off, 64);
            v1 += __shfl_xor(v1, off, 64);
        }

        if (lane == 0) {
            lds_log[(pi * 2 + 0) * 2 + ch] = logf(fabsf((float)v0));
            if (b1i < B)
                lds_log[(pi * 2 + 1) * 2 + ch] = logf(fabsf((float)v1));
        }
    }
    __syncthreads();
    if (threadIdx.x < 4) {
        int bb = blockIdx.x * 4 + threadIdx.x;
        if (bb < B)
            out[bb] = lds_log[threadIdx.x * 2 + 0] + lds_log[threadIdx.x * 2 + 1];
    }
}

extern "C" void kernel_launch(void* const* d_in, const int* in_sizes, int n_in,
                              void* d_out, int out_size, void* d_ws, size_t ws_size,
                              hipStream_t stream) {
    const float* x1  = (const float*)d_in[0];
    const float* x2  = (const float*)d_in[1];
    const float* W1a = (const float*)d_in[2];
    const float* b1a = (const float*)d_in[3];
    const float* W2a = (const float*)d_in[4];
    // d_in[5] = b2a: contributes b2 * sum(signs) = 0 exactly
    const float* W1b = (const float*)d_in[6];
    const float* b1b = (const float*)d_in[7];
    const float* W2b = (const float*)d_in[8];
    // d_in[9] = b2b: same

    const int B = in_sizes[0] / 18;  // (B, 6, 3) flattened
    float* out = (float*)d_out;

    dim3 grid((B + 3) / 4), block(256);  // 4 batch per block (2 per wave, packed)
    hipLaunchKernelGGL(antisym_kernel, grid, block, 0, stream,
                       x1, x2, W1a, b1a, W2a, W1b, b1b, W2b, out, B);
}